// Round 14
// baseline (289.749 us; speedup 1.0000x reference)
//
#include <hip/hip_runtime.h>
#include <hip/hip_bf16.h>
#include <hip/hip_fp16.h>

// RGCN: 3 layers of basis-decomposed relational graph conv + predictor.
// CSR build via 2-level counting sort (NO global atomics). Edge lists
//   PADDED to multiples of 8 per node (dummy rel=4, comp[4]=0, src=0):
//   mask-free batches that never span nodes. Pack: src | et<<17 | dl<<20.
// k_aggregate: 3-STAGE pipelined gather — per phase: pk-fetch batch k+2,
//   gather batch k+1 (its pk already resident), consume batch k. Decouples
//   pk-load latency from gather latency (R13's 2-slot still serialized
//   pk->gather inside ISSUE). ~16 gathers + 8 pk-loads in flight per wave.
// k_gemm_mfma: out = relu([Z|x] @ [bases;loop_w] + bias) via
//   mfma_f32_16x16x32_f16; W^T fp16 + residual in LDS (~2^-22 weight err).
//   Last layer fuses predictor: sigmoid(out @ pred_w + pred_b).

#define NB1 196        // ceil(100000/512) coarse buckets
#define NBLK1 256      // L1 partition blocks
#define BUCKET_SHIFT 9 // 512 nodes per bucket
#define PAD_ALLOW 4096 // per-bucket padding allowance (512 nodes x <=8)
#define WT_LD 200      // padded k-stride (fp16) for W^T LDS
#define DUMMY_PK (4 << 17)
#define WNODES 8       // nodes per wave in aggregate

typedef unsigned short ushort_t;
typedef _Float16 h8 __attribute__((ext_vector_type(8)));
typedef float f32x4 __attribute__((ext_vector_type(4)));

__device__ inline ushort_t f2h(float f) {
  __half h = __float2half_rn(f);
  return *(ushort_t*)&h;
}
__device__ inline float h2f(ushort_t u) {
  __half h = *(__half*)&u;
  return __half2float(h);
}

// inclusive scan of one int per thread across a 256-thread block
__device__ inline int block_incl_scan_256(int v, int* wsums) {
  int lane = threadIdx.x & 63, wid = threadIdx.x >> 6;
  int s = v;
#pragma unroll
  for (int off = 1; off < 64; off <<= 1) {
    int u = __shfl_up(s, off, 64);
    if (lane >= off) s += u;
  }
  if (lane == 63) wsums[wid] = s;
  __syncthreads();
  if (threadIdx.x == 0) {
    int a = 0;
#pragma unroll
    for (int w = 0; w < 4; ++w) { int t = wsums[w]; wsums[w] = a; a += t; }
  }
  __syncthreads();
  return s + wsums[wid];
}

// ---- L1 pass a: per-block LDS histogram over 196 coarse buckets
__global__ void __launch_bounds__(256) k_l1hist(const int* __restrict__ dst,
                                                int* __restrict__ H, int E, int chunk) {
  __shared__ int h[NB1];
  int t = threadIdx.x;
  if (t < NB1) h[t] = 0;
  __syncthreads();
  int beg = blockIdx.x * chunk;
  int end = min(beg + chunk, E);
  for (int i = beg + t; i < end; i += 256) atomicAdd(&h[dst[i] >> BUCKET_SHIFT], 1);
  __syncthreads();
  if (t < NB1) H[blockIdx.x * NB1 + t] = h[t];
}

// ---- L1 pass b: scan each bucket's column of H -> excl offsets + totals
__global__ void __launch_bounds__(256) k_colscan(int* __restrict__ H,
                                                 int* __restrict__ total) {
  __shared__ int wsums[4];
  int b = blockIdx.x;
  int t = threadIdx.x;
  int v = H[t * NB1 + b];
  int s = block_incl_scan_256(v, wsums);
  H[t * NB1 + b] = s - v;
  if (t == 255) total[b] = s;
}

// ---- L1 pass c: scan bucket totals -> bucket_base
__global__ void __launch_bounds__(256) k_basescan(const int* __restrict__ total,
                                                  int* __restrict__ bucket_base) {
  __shared__ int wsums[4];
  int t = threadIdx.x;
  int v = (t < NB1) ? total[t] : 0;
  int s = block_incl_scan_256(v, wsums);
  if (t < NB1) bucket_base[t] = s - v;
  if (t == 255) bucket_base[NB1] = s;
}

// ---- L1 pass d: scatter edges into bucket-partitioned epk1 via LDS cursors
__global__ void __launch_bounds__(256) k_scatter1(
    const int* __restrict__ src, const int* __restrict__ dst,
    const int* __restrict__ et, const int* __restrict__ H,
    const int* __restrict__ bucket_base, int* __restrict__ epk1,
    int E, int chunk) {
  __shared__ int cur[NB1];
  int t = threadIdx.x;
  if (t < NB1) cur[t] = bucket_base[t] + H[blockIdx.x * NB1 + t];
  __syncthreads();
  int beg = blockIdx.x * chunk;
  int end = min(beg + chunk, E);
  for (int i = beg + t; i < end; i += 256) {
    int d = dst[i];
    int b = d >> BUCKET_SHIFT;
    int p = atomicAdd(&cur[b], 1);
    epk1[p] = src[i] | (et[i] << 17) | ((d & 511) << 20);
  }
}

// ---- L2: per-bucket sort by dst_local (512 bins) into PADDED epk
__global__ void __launch_bounds__(256) k_bucket(
    const int* __restrict__ epk1, const int* __restrict__ bucket_base,
    int* __restrict__ epk, int* __restrict__ row_off,
    int* __restrict__ row_end, int N) {
  __shared__ int hist[512];
  __shared__ int cur[512];
  __shared__ int wsums[4];
  int b = blockIdx.x;
  int t = threadIdx.x;
  int ebase = bucket_base[b], eend = bucket_base[b + 1];
  int pb = ebase + b * PAD_ALLOW;   // padded region base
  hist[t] = 0; hist[t + 256] = 0;
  __syncthreads();
  for (int i = ebase + t; i < eend; i += 256) atomicAdd(&hist[epk1[i] >> 20], 1);
  __syncthreads();
  int h0 = hist[2 * t], h1 = hist[2 * t + 1];
  int pd0 = (h0 == 0) ? 8 : ((h0 + 7) & ~7);
  int pd1 = (h1 == 0) ? 8 : ((h1 + 7) & ~7);
  int pair = pd0 + pd1;
  int incl = block_incl_scan_256(pair, wsums);
  int pe0 = incl - pair;
  int s0 = pb + pe0, s1 = pb + pe0 + pd0;
  cur[2 * t] = s0;
  cur[2 * t + 1] = s1;
  int n0 = (b << BUCKET_SHIFT) + 2 * t;
  if (n0 < N)     { row_off[n0] = s0;     row_end[n0] = s0 + pd0; }
  if (n0 + 1 < N) { row_off[n0 + 1] = s1; row_end[n0 + 1] = s1 + pd1; }
  for (int p = s0 + h0; p < s0 + pd0; ++p) epk[p] = DUMMY_PK;
  for (int p = s1 + h1; p < s1 + pd1; ++p) epk[p] = DUMMY_PK;
  __syncthreads();
  for (int i = ebase + t; i < eend; i += 256) {
    int pk = epk1[i];
    int p = atomicAdd(&cur[pk >> 20], 1);
    epk[p] = pk;
  }
}

// ---- quantize fp32 -> fp16 (RTNE), vectorized
__global__ void __launch_bounds__(256) k_quant(const float* __restrict__ in,
                                               ushort_t* __restrict__ out, int n4) {
  int i = blockIdx.x * blockDim.x + threadIdx.x;
  if (i < n4) {
    float4 v = ((const float4*)in)[i];
    ushort4 q;
    q.x = f2h(v.x); q.y = f2h(v.y);
    q.z = f2h(v.z); q.w = f2h(v.w);
    ((ushort4*)out)[i] = q;
  }
}

// ---- 3-stage pipelined aggregate: wave = WNODES sequential nodes.
// Phases rotate slots {A,B,C}: pk-fetch k+2 | gather k+1 | consume k.
__global__ void __launch_bounds__(256) k_aggregate(
    const ushort_t* __restrict__ xq, const int* __restrict__ row_off,
    const int* __restrict__ row_end, const int* __restrict__ epk,
    const float* __restrict__ comp, ushort_t* __restrict__ Zh, int N) {
  __shared__ float2 s_comp[5];
  if (threadIdx.x < 5) {
    float2 c2;
    c2.x = (threadIdx.x < 4) ? comp[threadIdx.x * 2 + 0] : 0.f;
    c2.y = (threadIdx.x < 4) ? comp[threadIdx.x * 2 + 1] : 0.f;
    s_comp[threadIdx.x] = c2;
  }
  __syncthreads();
  int lane = threadIdx.x & 63;
  int wnode0 = (blockIdx.x * 4 + (threadIdx.x >> 6)) * WNODES;
  if (wnode0 >= N) return;
  int wnode1 = min(wnode0 + WNODES, N);

  // pk-fetch cursor (wave-uniform)
  int nj = wnode0;
  int ej = row_off[nj], ejEnd = row_end[nj];

  int pkA[8], pkB[8], pkC[8];
  ushort_t xvA[8], xvB[8], xvC[8];
  int nodeA = wnode0, nodeB = wnode0, nodeC = wnode0;

#define PKFETCH(PK, NODE)                                                   \
  {                                                                         \
    NODE = nj;                                                              \
    _Pragma("unroll") for (int u = 0; u < 8; ++u) PK[u] = epk[ej + u];      \
    ej += 8;                                                                \
    if (ej >= ejEnd) {                                                      \
      if (nj + 1 < wnode1) { ++nj; ej = row_off[nj]; ejEnd = row_end[nj]; } \
      else nj = -1;                                                         \
    }                                                                       \
  }

#define GATHER(PK, XV)                                                      \
  {                                                                         \
    _Pragma("unroll") for (int u = 0; u < 8; ++u)                           \
        XV[u] = xq[(size_t)(PK[u] & 0x1FFFF) * 64 + lane];                  \
  }

  int ncons = wnode0;
  float z0 = 0.f, z1 = 0.f;

#define CONSUME(PK, XV, NODE)                                               \
  {                                                                         \
    if (NODE != ncons) {                                                    \
      Zh[(size_t)ncons * 128 + lane] = f2h(z0);                             \
      Zh[(size_t)ncons * 128 + 64 + lane] = f2h(z1);                        \
      z0 = 0.f; z1 = 0.f; ncons = NODE;                                     \
    }                                                                       \
    _Pragma("unroll") for (int u = 0; u < 8; ++u) {                         \
      float2 cp = s_comp[(PK[u] >> 17) & 7];                                \
      float xf = h2f(XV[u]);                                                \
      z0 = fmaf(cp.x, xf, z0);                                              \
      z1 = fmaf(cp.y, xf, z1);                                              \
    }                                                                       \
  }

  // prologue
  PKFETCH(pkA, nodeA);
  bool haveB = (nj >= 0);
  if (haveB) PKFETCH(pkB, nodeB);
  GATHER(pkA, xvA);
  bool haveA = true, haveC = false;
  for (;;) {
    haveC = (nj >= 0);
    if (haveC) PKFETCH(pkC, nodeC);
    if (haveB) GATHER(pkB, xvB);
    CONSUME(pkA, xvA, nodeA);
    if (!haveB) break;
    haveA = (nj >= 0);
    if (haveA) PKFETCH(pkA, nodeA);
    if (haveC) GATHER(pkC, xvC);
    CONSUME(pkB, xvB, nodeB);
    if (!haveC) break;
    haveB = (nj >= 0);
    if (haveB) PKFETCH(pkB, nodeB);
    if (haveA) GATHER(pkA, xvA);
    CONSUME(pkC, xvC, nodeC);
    if (!haveA) break;
  }
  // final flush
  Zh[(size_t)ncons * 128 + lane] = f2h(z0);
  Zh[(size_t)ncons * 128 + 64 + lane] = f2h(z1);
#undef PKFETCH
#undef GATHER
#undef CONSUME
}

// ---- MFMA GEMM: out = relu([Z | x](64x192 fp16) @ W(192x64) + bias)
// A-frags from global (rows read once); W^T fp16 + residual in LDS.
// Optional fused predictor (last layer): sigmoid(out @ pw + pb).
// Layouts (mfma_f32_16x16x32_f16): A row=l&15, k=8*(l>>4)+j;
// B k=8*(l>>4)+j, col=l&15; C/D col=l&15, row=4*(l>>4)+reg.
__global__ void __launch_bounds__(256) k_gemm_mfma(
    const ushort_t* __restrict__ Zh, const ushort_t* __restrict__ xq,
    const float* __restrict__ bases, const float* __restrict__ loopw,
    const float* __restrict__ bias, ushort_t* __restrict__ xqOut,
    const float* __restrict__ pw, const float* __restrict__ pb,
    float* __restrict__ predOut, int N) {
  __shared__ ushort_t sWh[64 * WT_LD];  // W^T fp16:      25.6 KB
  __shared__ ushort_t sWr[64 * WT_LD];  // W^T residual:  25.6 KB
  int t = threadIdx.x;
  int w = t >> 6, l = t & 63;
  int lr = l & 15, lg = l >> 4;
  int row0 = blockIdx.x * 64 + w * 16;

  // ---- issue A-frag global loads FIRST (independent of LDS staging)
  int arow = row0 + lr;
  bool rok = arow < N;
  h8 a[6];
#pragma unroll
  for (int kb = 0; kb < 6; ++kb) {
    int k0 = kb * 32 + lg * 8;
    uint4 u = make_uint4(0, 0, 0, 0);
    if (rok) {
      if (kb < 4) u = *(const uint4*)(Zh + (size_t)arow * 128 + k0);
      else        u = *(const uint4*)(xq + (size_t)arow * 64 + (k0 - 128));
    }
    a[kb] = *(h8*)&u;
  }

  // ---- stage W^T as fp16 + residual (W = Wh + Wr exactly to ~2^-22)
#pragma unroll 4
  for (int i = 0; i < 48; ++i) {
    int idx = i * 256 + t;        // 0..12287
    int k = idx >> 6, c = idx & 63;
    float wv = (k < 128) ? bases[idx] : loopw[idx - 8192];
    ushort_t hh = f2h(wv);
    sWh[c * WT_LD + k] = hh;
    sWr[c * WT_LD + k] = f2h(wv - h2f(hh));
  }
  __syncthreads();

  // ---- MFMA: 4 col-tiles x 6 k-steps x (Wh + Wr)
  f32x4 acc[4];
#pragma unroll
  for (int c = 0; c < 4; ++c) acc[c] = (f32x4){0.f, 0.f, 0.f, 0.f};
#pragma unroll
  for (int c = 0; c < 4; ++c) {
    int col = c * 16 + lr;
    const ushort_t* bh = sWh + col * WT_LD + lg * 8;
    const ushort_t* br = sWr + col * WT_LD + lg * 8;
#pragma unroll
    for (int kb = 0; kb < 6; ++kb) {
      h8 vb = *(const h8*)(bh + kb * 32);
      acc[c] = __builtin_amdgcn_mfma_f32_16x16x32_f16(a[kb], vb, acc[c], 0, 0, 0);
      h8 vr = *(const h8*)(br + kb * 32);
      acc[c] = __builtin_amdgcn_mfma_f32_16x16x32_f16(a[kb], vr, acc[c], 0, 0, 0);
    }
  }

  // ---- epilogue: bias + relu
  float o_[4][4];
#pragma unroll
  for (int c = 0; c < 4; ++c) {
    float bv = bias[c * 16 + lr];
#pragma unroll
    for (int r = 0; r < 4; ++r) o_[c][r] = fmaxf(acc[c][r] + bv, 0.f);
  }
  if (xqOut) {
#pragma unroll
    for (int c = 0; c < 4; ++c) {
      int col = c * 16 + lr;
#pragma unroll
      for (int r = 0; r < 4; ++r) {
        int grow = row0 + lg * 4 + r;
        if (grow < N)
          xqOut[(size_t)grow * 64 + col] = f2h(o_[c][r]);
      }
    }
  }
  if (predOut) {
    float pwv[4];
#pragma unroll
    for (int c = 0; c < 4; ++c) pwv[c] = pw[c * 16 + lr];
#pragma unroll
    for (int r = 0; r < 4; ++r) {
      float s_ = o_[0][r] * pwv[0] + o_[1][r] * pwv[1] +
                 o_[2][r] * pwv[2] + o_[3][r] * pwv[3];
#pragma unroll
      for (int off = 1; off < 16; off <<= 1) s_ += __shfl_xor(s_, off, 64);
      int grow = row0 + lg * 4 + r;
      if (lr == 0 && grow < N) {
        float logit = s_ + pb[0];
        predOut[grow] = 1.f / (1.f + expf(-logit));
      }
    }
  }
}

extern "C" void kernel_launch(void* const* d_in, const int* in_sizes, int n_in,
                              void* d_out, int out_size, void* d_ws, size_t ws_size,
                              hipStream_t stream) {
  const float* features = (const float*)d_in[0];
  const int* src = (const int*)d_in[1];
  const int* dst = (const int*)d_in[2];
  const int* et  = (const int*)d_in[3];
  const float* bases[3] = {(const float*)d_in[4], (const float*)d_in[8],  (const float*)d_in[12]};
  const float* comp[3]  = {(const float*)d_in[5], (const float*)d_in[9],  (const float*)d_in[13]};
  const float* loopw[3] = {(const float*)d_in[6], (const float*)d_in[10], (const float*)d_in[14]};
  const float* biasp[3] = {(const float*)d_in[7], (const float*)d_in[11], (const float*)d_in[15]};
  const float* pred_w = (const float*)d_in[16];
  const float* pred_b = (const float*)d_in[17];

  const int N = in_sizes[0] / 64;   // 100000
  const int E = in_sizes[1];        // 1600000

  char* ws = (char*)d_ws;
  size_t off = 0;
  auto take = [&](size_t bytes) {
    char* p = ws + off;
    off += (bytes + 255) & ~(size_t)255;
    return p;
  };
  int*      row_off     = (int*)     take((size_t)(N + 1) * 4);
  int*      row_end     = (int*)     take((size_t)N * 4);
  int*      H           = (int*)     take((size_t)NBLK1 * NB1 * 4);
  int*      total       = (int*)     take((size_t)NB1 * 4);
  int*      bucket_base = (int*)     take((size_t)(NB1 + 1) * 4);
  int*      epk         = (int*)     take((size_t)(E + NB1 * PAD_ALLOW + 8) * 4);
  ushort_t* Zh          = (ushort_t*)take((size_t)N * 128 * 2);
  ushort_t* xqA         = (ushort_t*)take((size_t)N * 64 * 2);
  ushort_t* xqB         = (ushort_t*)take((size_t)N * 64 * 2);
  int*      epk1        = (int*)Zh;   // alias: Zh dead during CSR build
  (void)ws_size;

  // ---- CSR build: 2-level counting sort, no global atomics
  int chunk = (E + NBLK1 - 1) / NBLK1;
  k_l1hist  <<<NBLK1, 256, 0, stream>>>(dst, H, E, chunk);
  k_colscan <<<NB1,   256, 0, stream>>>(H, total);
  k_basescan<<<1,     256, 0, stream>>>(total, bucket_base);
  k_scatter1<<<NBLK1, 256, 0, stream>>>(src, dst, et, H, bucket_base, epk1, E, chunk);
  k_bucket  <<<NB1,   256, 0, stream>>>(epk1, bucket_base, epk, row_off, row_end, N);

  // ---- quantize input features to fp16
  k_quant<<<(N * 16 + 255) / 256, 256, 0, stream>>>(features, xqA, N * 16);

  // ---- 3 RGCN layers (fp16 activations ping-pong); layer 3 fuses predictor
  ushort_t* bufs[2] = {xqA, xqB};
  int agg_grid = (N + 4 * WNODES - 1) / (4 * WNODES);
  int gemm_grid = (N + 63) / 64;
  for (int l = 0; l < 3; ++l) {
    k_aggregate<<<agg_grid, 256, 0, stream>>>(bufs[l & 1], row_off, row_end,
                                              epk, comp[l], Zh, N);
    bool last = (l == 2);
    k_gemm_mfma<<<gemm_grid, 256, 0, stream>>>(
        Zh, bufs[l & 1], bases[l], loopw[l], biasp[l],
        last ? nullptr : bufs[(l + 1) & 1],
        pred_w, pred_b, last ? (float*)d_out : nullptr, N);
  }
}

// Round 15
// 276.574 us; speedup vs baseline: 1.0476x; 1.0476x over previous
//
#include <hip/hip_runtime.h>
#include <hip/hip_bf16.h>
#include <hip/hip_fp16.h>

// RGCN: 3 layers of basis-decomposed relational graph conv + predictor.
// CSR build via 2-level counting sort (NO global atomics). Edge lists are
//   PADDED to multiples of 8 per node with dummy edges (rel=4, comp[4]=0,
//   src=0) so the aggregate hot loop is mask-free and batches never span
//   nodes. Pack: src | et<<17 (3 bits) | dst_local<<20.
// k_aggregate: SOFTWARE-PIPELINED gather (2-slot ping-pong): issue batch
//   k+1's 8 gathers BEFORE consuming batch k -> counted vmcnt, ~16 gathers
//   in flight/wave. Depth=2 is the optimum: R14's 3-stage variant cost
//   +8 VGPR / -10% occupancy and regressed 54->60us. Wave = 8 nodes.
// k_gemm_mfma: out = relu([Z|x] @ [bases;loop_w] + bias) via
//   mfma_f32_16x16x32_f16; W^T fp16 + residual in LDS (~2^-22 weight err).
//   Last layer fuses predictor: sigmoid(out @ pred_w + pred_b).

#define NB1 196        // ceil(100000/512) coarse buckets
#define NBLK1 256      // L1 partition blocks
#define BUCKET_SHIFT 9 // 512 nodes per bucket
#define PAD_ALLOW 4096 // per-bucket padding allowance (512 nodes x <=8)
#define WT_LD 200      // padded k-stride (fp16) for W^T LDS
#define DUMMY_PK (4 << 17)
#define WNODES 8       // nodes per wave in aggregate

typedef unsigned short ushort_t;
typedef _Float16 h8 __attribute__((ext_vector_type(8)));
typedef float f32x4 __attribute__((ext_vector_type(4)));

__device__ inline ushort_t f2h(float f) {
  __half h = __float2half_rn(f);
  return *(ushort_t*)&h;
}
__device__ inline float h2f(ushort_t u) {
  __half h = *(__half*)&u;
  return __half2float(h);
}

// inclusive scan of one int per thread across a 256-thread block
__device__ inline int block_incl_scan_256(int v, int* wsums) {
  int lane = threadIdx.x & 63, wid = threadIdx.x >> 6;
  int s = v;
#pragma unroll
  for (int off = 1; off < 64; off <<= 1) {
    int u = __shfl_up(s, off, 64);
    if (lane >= off) s += u;
  }
  if (lane == 63) wsums[wid] = s;
  __syncthreads();
  if (threadIdx.x == 0) {
    int a = 0;
#pragma unroll
    for (int w = 0; w < 4; ++w) { int t = wsums[w]; wsums[w] = a; a += t; }
  }
  __syncthreads();
  return s + wsums[wid];
}

// ---- L1 pass a: per-block LDS histogram over 196 coarse buckets
__global__ void __launch_bounds__(256) k_l1hist(const int* __restrict__ dst,
                                                int* __restrict__ H, int E, int chunk) {
  __shared__ int h[NB1];
  int t = threadIdx.x;
  if (t < NB1) h[t] = 0;
  __syncthreads();
  int beg = blockIdx.x * chunk;
  int end = min(beg + chunk, E);
  for (int i = beg + t; i < end; i += 256) atomicAdd(&h[dst[i] >> BUCKET_SHIFT], 1);
  __syncthreads();
  if (t < NB1) H[blockIdx.x * NB1 + t] = h[t];
}

// ---- L1 pass b: scan each bucket's column of H -> excl offsets + totals
__global__ void __launch_bounds__(256) k_colscan(int* __restrict__ H,
                                                 int* __restrict__ total) {
  __shared__ int wsums[4];
  int b = blockIdx.x;
  int t = threadIdx.x;
  int v = H[t * NB1 + b];
  int s = block_incl_scan_256(v, wsums);
  H[t * NB1 + b] = s - v;
  if (t == 255) total[b] = s;
}

// ---- L1 pass c: scan bucket totals -> bucket_base
__global__ void __launch_bounds__(256) k_basescan(const int* __restrict__ total,
                                                  int* __restrict__ bucket_base) {
  __shared__ int wsums[4];
  int t = threadIdx.x;
  int v = (t < NB1) ? total[t] : 0;
  int s = block_incl_scan_256(v, wsums);
  if (t < NB1) bucket_base[t] = s - v;
  if (t == 255) bucket_base[NB1] = s;
}

// ---- L1 pass d: scatter edges into bucket-partitioned epk1 via LDS cursors
__global__ void __launch_bounds__(256) k_scatter1(
    const int* __restrict__ src, const int* __restrict__ dst,
    const int* __restrict__ et, const int* __restrict__ H,
    const int* __restrict__ bucket_base, int* __restrict__ epk1,
    int E, int chunk) {
  __shared__ int cur[NB1];
  int t = threadIdx.x;
  if (t < NB1) cur[t] = bucket_base[t] + H[blockIdx.x * NB1 + t];
  __syncthreads();
  int beg = blockIdx.x * chunk;
  int end = min(beg + chunk, E);
  for (int i = beg + t; i < end; i += 256) {
    int d = dst[i];
    int b = d >> BUCKET_SHIFT;
    int p = atomicAdd(&cur[b], 1);
    epk1[p] = src[i] | (et[i] << 17) | ((d & 511) << 20);
  }
}

// ---- L2: per-bucket sort by dst_local (512 bins) into PADDED epk
// (each node's segment rounded up to a multiple of 8; pads = DUMMY_PK).
__global__ void __launch_bounds__(256) k_bucket(
    const int* __restrict__ epk1, const int* __restrict__ bucket_base,
    int* __restrict__ epk, int* __restrict__ row_off,
    int* __restrict__ row_end, int N) {
  __shared__ int hist[512];
  __shared__ int cur[512];
  __shared__ int wsums[4];
  int b = blockIdx.x;
  int t = threadIdx.x;
  int ebase = bucket_base[b], eend = bucket_base[b + 1];
  int pb = ebase + b * PAD_ALLOW;   // padded region base
  hist[t] = 0; hist[t + 256] = 0;
  __syncthreads();
  for (int i = ebase + t; i < eend; i += 256) atomicAdd(&hist[epk1[i] >> 20], 1);
  __syncthreads();
  int h0 = hist[2 * t], h1 = hist[2 * t + 1];
  int pd0 = (h0 == 0) ? 8 : ((h0 + 7) & ~7);
  int pd1 = (h1 == 0) ? 8 : ((h1 + 7) & ~7);
  int pair = pd0 + pd1;
  int incl = block_incl_scan_256(pair, wsums);
  int pe0 = incl - pair;
  int s0 = pb + pe0, s1 = pb + pe0 + pd0;
  cur[2 * t] = s0;
  cur[2 * t + 1] = s1;
  int n0 = (b << BUCKET_SHIFT) + 2 * t;
  if (n0 < N)     { row_off[n0] = s0;     row_end[n0] = s0 + pd0; }
  if (n0 + 1 < N) { row_off[n0 + 1] = s1; row_end[n0 + 1] = s1 + pd1; }
  // fill pad slots (disjoint from scatter targets; no sync needed)
  for (int p = s0 + h0; p < s0 + pd0; ++p) epk[p] = DUMMY_PK;
  for (int p = s1 + h1; p < s1 + pd1; ++p) epk[p] = DUMMY_PK;
  __syncthreads();
  for (int i = ebase + t; i < eend; i += 256) {
    int pk = epk1[i];
    int p = atomicAdd(&cur[pk >> 20], 1);
    epk[p] = pk;
  }
}

// ---- quantize fp32 -> fp16 (RTNE), vectorized
__global__ void __launch_bounds__(256) k_quant(const float* __restrict__ in,
                                               ushort_t* __restrict__ out, int n4) {
  int i = blockIdx.x * blockDim.x + threadIdx.x;
  if (i < n4) {
    float4 v = ((const float4*)in)[i];
    ushort4 q;
    q.x = f2h(v.x); q.y = f2h(v.y);
    q.z = f2h(v.z); q.w = f2h(v.w);
    ((ushort4*)out)[i] = q;
  }
}

// ---- pipelined aggregate: wave = WNODES sequential nodes; two batch slots
// ping-pong so ~16 gathers stay in flight while consuming the previous 8.
// Batches are mask-free (padded edge lists; comp[4]=0 kills dummies).
__global__ void __launch_bounds__(256) k_aggregate(
    const ushort_t* __restrict__ xq, const int* __restrict__ row_off,
    const int* __restrict__ row_end, const int* __restrict__ epk,
    const float* __restrict__ comp, ushort_t* __restrict__ Zh, int N) {
  __shared__ float s_comp[10];
  if (threadIdx.x < 10)
    s_comp[threadIdx.x] = (threadIdx.x < 8) ? comp[threadIdx.x] : 0.f;
  __syncthreads();
  int lane = threadIdx.x & 63;
  int wnode0 = (blockIdx.x * 4 + (threadIdx.x >> 6)) * WNODES;
  if (wnode0 >= N) return;
  int wnode1 = min(wnode0 + WNODES, N);

  // issue cursor (wave-uniform)
  int nj = wnode0;
  int ej = row_off[nj], ejEnd = row_end[nj];

  int pkA[8], pkB[8];
  ushort_t xvA[8], xvB[8];
  int nodeA = wnode0, nodeB = wnode0;

#define ISSUE(PK, XV, NODE)                                                 \
  {                                                                         \
    NODE = nj;                                                              \
    _Pragma("unroll") for (int u = 0; u < 8; ++u) PK[u] = epk[ej + u];      \
    _Pragma("unroll") for (int u = 0; u < 8; ++u)                           \
        XV[u] = xq[(size_t)(PK[u] & 0x1FFFF) * 64 + lane];                  \
    ej += 8;                                                                \
    if (ej >= ejEnd) {                                                      \
      if (nj + 1 < wnode1) { ++nj; ej = row_off[nj]; ejEnd = row_end[nj]; } \
      else nj = -1;                                                         \
    }                                                                       \
  }

  int ncons = wnode0;
  float z0 = 0.f, z1 = 0.f;

#define CONSUME(PK, XV, NODE)                                               \
  {                                                                         \
    if (NODE != ncons) {                                                    \
      Zh[(size_t)ncons * 128 + lane] = f2h(z0);                             \
      Zh[(size_t)ncons * 128 + 64 + lane] = f2h(z1);                        \
      z0 = 0.f; z1 = 0.f; ncons = NODE;                                     \
    }                                                                       \
    _Pragma("unroll") for (int u = 0; u < 8; ++u) {                         \
      int r = (PK[u] >> 17) & 7;                                            \
      float xf = h2f(XV[u]);                                                \
      z0 = fmaf(s_comp[r * 2 + 0], xf, z0);                                 \
      z1 = fmaf(s_comp[r * 2 + 1], xf, z1);                                 \
    }                                                                       \
  }

  ISSUE(pkA, xvA, nodeA);
  for (;;) {
    bool haveB = (nj >= 0);
    if (haveB) ISSUE(pkB, xvB, nodeB);
    CONSUME(pkA, xvA, nodeA);
    if (!haveB) break;
    bool haveA = (nj >= 0);
    if (haveA) ISSUE(pkA, xvA, nodeA);
    CONSUME(pkB, xvB, nodeB);
    if (!haveA) break;
  }
  // final flush
  Zh[(size_t)ncons * 128 + lane] = f2h(z0);
  Zh[(size_t)ncons * 128 + 64 + lane] = f2h(z1);
#undef ISSUE
#undef CONSUME
}

// ---- MFMA GEMM: out = relu([Z | x](64x192 fp16) @ W(192x64) + bias)
// A-frags from global (rows read once); W^T fp16 + residual in LDS.
// Optional fused predictor (last layer): sigmoid(out @ pw + pb).
// Layouts (mfma_f32_16x16x32_f16): A row=l&15, k=8*(l>>4)+j;
// B k=8*(l>>4)+j, col=l&15; C/D col=l&15, row=4*(l>>4)+reg.
__global__ void __launch_bounds__(256) k_gemm_mfma(
    const ushort_t* __restrict__ Zh, const ushort_t* __restrict__ xq,
    const float* __restrict__ bases, const float* __restrict__ loopw,
    const float* __restrict__ bias, ushort_t* __restrict__ xqOut,
    const float* __restrict__ pw, const float* __restrict__ pb,
    float* __restrict__ predOut, int N) {
  __shared__ ushort_t sWh[64 * WT_LD];  // W^T fp16:      25.6 KB
  __shared__ ushort_t sWr[64 * WT_LD];  // W^T residual:  25.6 KB
  int t = threadIdx.x;
  int w = t >> 6, l = t & 63;
  int lr = l & 15, lg = l >> 4;
  int row0 = blockIdx.x * 64 + w * 16;

  // ---- issue A-frag global loads FIRST (independent of LDS staging)
  int arow = row0 + lr;
  bool rok = arow < N;
  h8 a[6];
#pragma unroll
  for (int kb = 0; kb < 6; ++kb) {
    int k0 = kb * 32 + lg * 8;
    uint4 u = make_uint4(0, 0, 0, 0);
    if (rok) {
      if (kb < 4) u = *(const uint4*)(Zh + (size_t)arow * 128 + k0);
      else        u = *(const uint4*)(xq + (size_t)arow * 64 + (k0 - 128));
    }
    a[kb] = *(h8*)&u;
  }

  // ---- stage W^T as fp16 + residual (W = Wh + Wr exactly to ~2^-22)
#pragma unroll 4
  for (int i = 0; i < 48; ++i) {
    int idx = i * 256 + t;        // 0..12287
    int k = idx >> 6, c = idx & 63;
    float wv = (k < 128) ? bases[idx] : loopw[idx - 8192];
    ushort_t hh = f2h(wv);
    sWh[c * WT_LD + k] = hh;
    sWr[c * WT_LD + k] = f2h(wv - h2f(hh));
  }
  __syncthreads();

  // ---- MFMA: 4 col-tiles x 6 k-steps x (Wh + Wr)
  f32x4 acc[4];
#pragma unroll
  for (int c = 0; c < 4; ++c) acc[c] = (f32x4){0.f, 0.f, 0.f, 0.f};
#pragma unroll
  for (int c = 0; c < 4; ++c) {
    int col = c * 16 + lr;
    const ushort_t* bh = sWh + col * WT_LD + lg * 8;
    const ushort_t* br = sWr + col * WT_LD + lg * 8;
#pragma unroll
    for (int kb = 0; kb < 6; ++kb) {
      h8 vb = *(const h8*)(bh + kb * 32);
      acc[c] = __builtin_amdgcn_mfma_f32_16x16x32_f16(a[kb], vb, acc[c], 0, 0, 0);
      h8 vr = *(const h8*)(br + kb * 32);
      acc[c] = __builtin_amdgcn_mfma_f32_16x16x32_f16(a[kb], vr, acc[c], 0, 0, 0);
    }
  }

  // ---- epilogue: bias + relu
  float o_[4][4];
#pragma unroll
  for (int c = 0; c < 4; ++c) {
    float bv = bias[c * 16 + lr];
#pragma unroll
    for (int r = 0; r < 4; ++r) o_[c][r] = fmaxf(acc[c][r] + bv, 0.f);
  }
  if (xqOut) {
#pragma unroll
    for (int c = 0; c < 4; ++c) {
      int col = c * 16 + lr;
#pragma unroll
      for (int r = 0; r < 4; ++r) {
        int grow = row0 + lg * 4 + r;
        if (grow < N)
          xqOut[(size_t)grow * 64 + col] = f2h(o_[c][r]);
      }
    }
  }
  if (predOut) {
    float pwv[4];
#pragma unroll
    for (int c = 0; c < 4; ++c) pwv[c] = pw[c * 16 + lr];
#pragma unroll
    for (int r = 0; r < 4; ++r) {
      float s_ = o_[0][r] * pwv[0] + o_[1][r] * pwv[1] +
                 o_[2][r] * pwv[2] + o_[3][r] * pwv[3];
#pragma unroll
      for (int off = 1; off < 16; off <<= 1) s_ += __shfl_xor(s_, off, 64);
      int grow = row0 + lg * 4 + r;
      if (lr == 0 && grow < N) {
        float logit = s_ + pb[0];
        predOut[grow] = 1.f / (1.f + expf(-logit));
      }
    }
  }
}

extern "C" void kernel_launch(void* const* d_in, const int* in_sizes, int n_in,
                              void* d_out, int out_size, void* d_ws, size_t ws_size,
                              hipStream_t stream) {
  const float* features = (const float*)d_in[0];
  const int* src = (const int*)d_in[1];
  const int* dst = (const int*)d_in[2];
  const int* et  = (const int*)d_in[3];
  const float* bases[3] = {(const float*)d_in[4], (const float*)d_in[8],  (const float*)d_in[12]};
  const float* comp[3]  = {(const float*)d_in[5], (const float*)d_in[9],  (const float*)d_in[13]};
  const float* loopw[3] = {(const float*)d_in[6], (const float*)d_in[10], (const float*)d_in[14]};
  const float* biasp[3] = {(const float*)d_in[7], (const float*)d_in[11], (const float*)d_in[15]};
  const float* pred_w = (const float*)d_in[16];
  const float* pred_b = (const float*)d_in[17];

  const int N = in_sizes[0] / 64;   // 100000
  const int E = in_sizes[1];        // 1600000

  char* ws = (char*)d_ws;
  size_t off = 0;
  auto take = [&](size_t bytes) {
    char* p = ws + off;
    off += (bytes + 255) & ~(size_t)255;
    return p;
  };
  int*      row_off     = (int*)     take((size_t)(N + 1) * 4);
  int*      row_end     = (int*)     take((size_t)N * 4);
  int*      H           = (int*)     take((size_t)NBLK1 * NB1 * 4);
  int*      total       = (int*)     take((size_t)NB1 * 4);
  int*      bucket_base = (int*)     take((size_t)(NB1 + 1) * 4);
  int*      epk         = (int*)     take((size_t)(E + NB1 * PAD_ALLOW + 8) * 4);
  ushort_t* Zh          = (ushort_t*)take((size_t)N * 128 * 2);
  ushort_t* xqA         = (ushort_t*)take((size_t)N * 64 * 2);
  ushort_t* xqB         = (ushort_t*)take((size_t)N * 64 * 2);
  int*      epk1        = (int*)Zh;   // alias: Zh dead during CSR build
  (void)ws_size;

  // ---- CSR build: 2-level counting sort, no global atomics
  int chunk = (E + NBLK1 - 1) / NBLK1;
  k_l1hist  <<<NBLK1, 256, 0, stream>>>(dst, H, E, chunk);
  k_colscan <<<NB1,   256, 0, stream>>>(H, total);
  k_basescan<<<1,     256, 0, stream>>>(total, bucket_base);
  k_scatter1<<<NBLK1, 256, 0, stream>>>(src, dst, et, H, bucket_base, epk1, E, chunk);
  k_bucket  <<<NB1,   256, 0, stream>>>(epk1, bucket_base, epk, row_off, row_end, N);

  // ---- quantize input features to fp16
  k_quant<<<(N * 16 + 255) / 256, 256, 0, stream>>>(features, xqA, N * 16);

  // ---- 3 RGCN layers (fp16 activations ping-pong); layer 3 fuses predictor
  ushort_t* bufs[2] = {xqA, xqB};
  int agg_grid = (N + 4 * WNODES - 1) / (4 * WNODES);
  int gemm_grid = (N + 63) / 64;
  for (int l = 0; l < 3; ++l) {
    k_aggregate<<<agg_grid, 256, 0, stream>>>(bufs[l & 1], row_off, row_end,
                                              epk, comp[l], Zh, N);
    bool last = (l == 2);
    k_gemm_mfma<<<gemm_grid, 256, 0, stream>>>(
        Zh, bufs[l & 1], bases[l], loopw[l], biasp[l],
        last ? nullptr : bufs[(l + 1) & 1],
        pred_w, pred_b, last ? (float*)d_out : nullptr, N);
  }
}